// Round 1
// baseline (162.438 us; speedup 1.0000x reference)
//
#include <hip/hip_runtime.h>

// ROI bilinear pooling (TF1 resize_images align_corners=False semantics).
// img: (1, H=100, W=100, C=1024) f32 NHWC
// rois: (1, R=512, 4) f32 holding integer-valued x,y,w,h
// out: (1, R, 7, 7, C) f32
//
// One block per (roi, py, px); 256 threads x float4 = 1024 channels.
// All global accesses coalesced (consecutive lanes -> consecutive float4).

#define IMG_H 100
#define IMG_W 100
#define IMG_C 1024
#define N_ROI 512
#define POOLP 7

__global__ __launch_bounds__(256) void roi_pool_kernel(
    const float* __restrict__ img,
    const float* __restrict__ rois,
    float* __restrict__ out)
{
    const int p   = blockIdx.x;          // [0, N_ROI*49)
    const int roi = p / 49;
    const int pos = p - roi * 49;
    const int py  = pos / 7;
    const int px  = pos - py * 7;

    // rois layout (R,4): x,y,w,h as float-encoded ints
    const float4 rv = *reinterpret_cast<const float4*>(rois + roi * 4);
    const int x = (int)rv.x;
    const int y = (int)rv.y;
    const int w = (int)rv.z;
    const int h = (int)rv.w;

    // TF1 bilinear source coords: s = out_idx * (size / P)
    const float sx  = (float)px * ((float)w / (float)POOLP);
    const int   ix0 = (int)floorf(sx);
    const int   ix1 = min(ix0 + 1, w - 1);
    const float fx  = sx - (float)ix0;
    const int   ax0 = min(max(x + ix0, 0), IMG_W - 1);
    const int   ax1 = min(max(x + ix1, 0), IMG_W - 1);

    const float sy  = (float)py * ((float)h / (float)POOLP);
    const int   iy0 = (int)floorf(sy);
    const int   iy1 = min(iy0 + 1, h - 1);
    const float fy  = sy - (float)iy0;
    const int   ay0 = min(max(y + iy0, 0), IMG_H - 1);
    const int   ay1 = min(max(y + iy1, 0), IMG_H - 1);

    const float gx = 1.0f - fx;
    const float gy = 1.0f - fy;

    const int c = threadIdx.x << 2;   // 4 channels per thread

    const float4 v00 = *reinterpret_cast<const float4*>(
        img + ((size_t)ay0 * IMG_W + ax0) * IMG_C + c);
    const float4 v01 = *reinterpret_cast<const float4*>(
        img + ((size_t)ay0 * IMG_W + ax1) * IMG_C + c);
    const float4 v10 = *reinterpret_cast<const float4*>(
        img + ((size_t)ay1 * IMG_W + ax0) * IMG_C + c);
    const float4 v11 = *reinterpret_cast<const float4*>(
        img + ((size_t)ay1 * IMG_W + ax1) * IMG_C + c);

    float4 o;
    o.x = (v00.x * gx + v01.x * fx) * gy + (v10.x * gx + v11.x * fx) * fy;
    o.y = (v00.y * gx + v01.y * fx) * gy + (v10.y * gx + v11.y * fx) * fy;
    o.z = (v00.z * gx + v01.z * fx) * gy + (v10.z * gx + v11.z * fx) * fy;
    o.w = (v00.w * gx + v01.w * fx) * gy + (v10.w * gx + v11.w * fx) * fy;

    *reinterpret_cast<float4*>(out + (size_t)p * IMG_C + c) = o;
}

extern "C" void kernel_launch(void* const* d_in, const int* in_sizes, int n_in,
                              void* d_out, int out_size, void* d_ws, size_t ws_size,
                              hipStream_t stream)
{
    const float* img  = (const float*)d_in[0];
    const float* rois = (const float*)d_in[1];
    float* out = (float*)d_out;

    const int n_blocks = N_ROI * POOLP * POOLP;  // 25088
    roi_pool_kernel<<<n_blocks, 256, 0, stream>>>(img, rois, out);
}